// Round 5
// baseline (239.007 us; speedup 1.0000x reference)
//
#include <hip/hip_runtime.h>

// Spiking basal ganglia: T=512 serial LIF steps, B=256 circuits.
// R10 == R7 resubmit, now justified by R9's key datum: an L3-warm dispatch
// (52 GB/s HBM) ran the SAME 80us as cold (950 GB/s) => latency-structure-
// bound, not BW-bound. Chunk time ~= one load round-trip (no cross-chunk
// overlap); total = NCH x L. Fix: keep 3 chunks of register prefetch in
// flight ACROSS barriers -- producers use raw s_barrier + lgkmcnt(0) so
// vmcnt is only waited (counted, vmcnt(24)) at the register use point.
// R9 (same 8 waves, no pipeline) = 81us is the direct A/B baseline.
// Audited: barrier parity 18==18, disjoint buffer phasing, reg-set rotation
// safe, ~150 VGPR (9 waves fit). R7/R8 container failures attributed to
// infra (R9 shows recovered: preloaded inputs, normal push times).

__global__ __launch_bounds__(576, 1) void bg_kernel(
    const float* __restrict__ x,      // [T,B,2]
    const float* __restrict__ dopa,   // [T,B]
    const float* __restrict__ Wd1,    // [128,2]
    const float* __restrict__ Wd2,    // [128,2]
    const float* __restrict__ nd1,    // [T,B,128]
    const float* __restrict__ nd2,    // [T,B,128]
    float* __restrict__ out)          // [T,B]
{
#pragma clang fp contract(off)
    constexpr int T = 512, B = 256;
    constexpr int S = 32;             // steps per chunk
    constexpr int NCH = T / S;        // 16 chunks
    constexpr size_t TSTRIDE = (size_t)B * 128;   // noise t-stride (floats)

    __shared__ float lds_I[2][S][64][4];   // 64 KB: double-buffered currents
    __shared__ float lds_x[T][2];          // 4 KB
    __shared__ float lds_d[T];             // 2 KB

    const int b    = blockIdx.x;
    const int tid  = threadIdx.x;
    const int wv   = tid >> 6;        // 0 = consumer, 1..8 = producers
    const int lane = tid & 63;

    // ---- prologue A: stage x/dopa (all 576 threads) ----
    for (int t = tid; t < T; t += 576) {
        const float2 xv = *(const float2*)(x + (size_t)t * (B * 2) + b * 2);
        lds_x[t][0] = xv.x;
        lds_x[t][1] = xv.y;
        lds_d[t]    = dopa[(size_t)t * B + b];
    }
    __syncthreads();

    if (wv == 0) {
        // ================= CONSUMER (R5/R9's verified form) ======
        __syncthreads();   // matches producers' prologue barrier

        float v1a = 0.0f, v1b = 0.0f;
        float v2a = 0.0f, v2b = 0.0f;
        float v_stn = 0.0f, v_gpi = 0.0f;
        float gate_reg = 0.0f;

        for (int i = 0; i < NCH; ++i) {
            const float (*buf)[64][4] = lds_I[i & 1];

#pragma unroll
            for (int s = 0; s < S; ++s) {
                const float4 I = *(const float4*)&buf[s][lane][0];

                // ---- bit-identical recurrence (R2..R9 verified) ----
                v1a = 0.8f * v1a + 0.2f * I.x;
                v1b = 0.8f * v1b + 0.2f * I.y;
                v2a = 0.8f * v2a + 0.2f * I.z;
                v2b = 0.8f * v2b + 0.2f * I.w;

                const bool s1a = v1a >= 0.5f, s1b = v1b >= 0.5f;
                const bool s2a = v2a >= 0.5f, s2b = v2b >= 0.5f;
                v1a = s1a ? 0.0f : v1a;
                v1b = s1b ? 0.0f : v1b;
                v2a = s2a ? 0.0f : v2a;
                v2b = s2b ? 0.0f : v2b;

                const int c1 = __popcll(__ballot(s1a)) + __popcll(__ballot(s1b));
                const int c2 = __popcll(__ballot(s2a)) + __popcll(__ballot(s2b));
                const float mean1 = (float)c1 * 0.0078125f;
                const float mean2 = (float)c2 * 0.0078125f;

                const float I_stn = mean2 * 0.5f;
                v_stn = 0.8f * v_stn + 0.2f * I_stn;
                const float s_stn = (v_stn >= 0.5f) ? 1.0f : 0.0f;
                v_stn = (v_stn >= 0.5f) ? 0.0f : v_stn;

                const float I_gpi = (0.4f + mean1 * -0.8f) + s_stn * 0.6f;
                v_gpi = 0.8f * v_gpi + 0.2f * I_gpi;
                const float s_gpi = (v_gpi >= 0.5f) ? 1.0f : 0.0f;
                v_gpi = (v_gpi >= 0.5f) ? 0.0f : v_gpi;

                const float gate = mean1 - s_gpi;   // wave-uniform

                // lane ((i&1)*32 + s) latches step i*32+s's gate
                const int latch = ((i & 1) << 5) | s;
                gate_reg = (lane == latch) ? gate : gate_reg;
            }

            if (i & 1) {
                const int t0 = (i - 1) * S;
                out[(size_t)(t0 + lane) * B + b] = gate_reg;
            }

            __syncthreads();
        }
    } else {
        // ================= PRODUCERS (waves 1..8) =================
        const float4 w1 = *(const float4*)(Wd1 + 4 * lane);
        const float4 w2 = *(const float4*)(Wd2 + 4 * lane);
        const float* n1b = nd1 + (size_t)b * 128 + 2 * lane;
        const float* n2b = nd2 + (size_t)b * 128 + 2 * lane;
        const int p0 = (wv - 1) * 4;   // this wave covers steps p0..p0+3

        // 4 register sets: chunk c lives in set c&3. 3 chunks in flight.
        float2 r1[4][4], r2[4][4];

        // Issue the 8 loads (float2 x 4 steps x 2 arrays) for chunk c.
#define LOADC(c, st)                                                         \
        if ((c) < NCH) {                                                     \
            _Pragma("unroll")                                                \
            for (int j = 0; j < 4; ++j) {                                    \
                const size_t toff = (size_t)((c) * S + p0 + j) * TSTRIDE;    \
                r1[st][j] = *(const float2*)(n1b + toff);                    \
                r2[st][j] = *(const float2*)(n2b + toff);                    \
            }                                                                \
        }

        // Compute I for chunk c from set st, write into LDS buffer bf.
        // EXACT R2..R9 op sequence (contract off, fma dot) — bit-exact.
#define COMPC(c, st, bf)                                                     \
        if ((c) < NCH) {                                                     \
            _Pragma("unroll")                                                \
            for (int j = 0; j < 4; ++j) {                                    \
                const int s = p0 + j;                                        \
                const int t = (c) * S + s;                                   \
                const float xx = lds_x[t][0], xy = lds_x[t][1];              \
                const float dop = lds_d[t];                                  \
                const float m1 = 1.0f + dop * 0.5f;                          \
                const float m2 = 1.0f - dop * 0.3f;                          \
                const float dot1a = __builtin_fmaf(xy, w1.y, xx * w1.x);     \
                const float dot1b = __builtin_fmaf(xy, w1.w, xx * w1.z);     \
                const float dot2a = __builtin_fmaf(xy, w2.y, xx * w2.x);     \
                const float dot2b = __builtin_fmaf(xy, w2.w, xx * w2.z);     \
                float4 I;                                                    \
                I.x = dot1a * m1 + r1[st][j].x * 0.1f;                       \
                I.y = dot1b * m1 + r1[st][j].y * 0.1f;                       \
                I.z = dot2a * m2 + r2[st][j].x * 0.1f;                       \
                I.w = dot2b * m2 + r2[st][j].y * 0.1f;                       \
                *(float4*)&lds_I[bf][s][lane][0] = I;                        \
            }                                                                \
        }

        // Raw barrier: ds_writes must be visible (lgkmcnt 0) but global
        // loads stay in flight across it (vmcnt untouched).
#define PBAR                                                                 \
        __builtin_amdgcn_sched_barrier(0);                                   \
        asm volatile("s_waitcnt lgkmcnt(0)" ::: "memory");                   \
        __builtin_amdgcn_sched_barrier(0);                                   \
        __builtin_amdgcn_s_barrier();                                        \
        __builtin_amdgcn_sched_barrier(0);

        // prologue B: fill the pipeline 3 chunks deep, complete chunk 0
        LOADC(0, 0)
        LOADC(1, 1)
        LOADC(2, 2)
        LOADC(3, 3)
        COMPC(0, 0, 0)
        PBAR

#pragma unroll
        for (int i = 0; i < NCH; ++i) {
            LOADC(i + 4, (i + 4) & 3)          // keep 3 chunks in flight
            COMPC(i + 1, (i + 1) & 3, (i + 1) & 1)
            PBAR
        }
#undef LOADC
#undef COMPC
#undef PBAR
    }
}

extern "C" void kernel_launch(void* const* d_in, const int* in_sizes, int n_in,
                              void* d_out, int out_size, void* d_ws, size_t ws_size,
                              hipStream_t stream) {
    const float* x    = (const float*)d_in[0];
    const float* dopa = (const float*)d_in[1];
    // d_in[2] = rpe — unused by the reference
    const float* Wd1  = (const float*)d_in[3];
    const float* Wd2  = (const float*)d_in[4];
    const float* nd1  = (const float*)d_in[5];
    const float* nd2  = (const float*)d_in[6];
    float* out = (float*)d_out;

    bg_kernel<<<dim3(256), dim3(576), 0, stream>>>(x, dopa, Wd1, Wd2, nd1, nd2, out);
}

// Round 6
// 195.971 us; speedup vs baseline: 1.2196x; 1.2196x over previous
//
#include <hip/hip_runtime.h>

// Spiking basal ganglia: T=512 serial LIF steps, B=256 circuits.
// R11: R10's cross-barrier pipeline, spill-proofed. R10 post-mortem: VGPR=84
// with WRITE_SIZE 4->78 MB, FETCH +37 MB == the float2 r1[4][4]/r2[4][4]
// prefetch arrays were demoted to SCRATCH (rule #20; 9-wave block caps VGPR
// ~170 and the pressure heuristic punted). The pipeline never existed; the
// regression was scratch round-trips. R9's facts stand: L3-warm == cold ==
// 81us => burst-drain is latency-bound, not BW-bound; fix = loads in flight
// ACROSS barriers. This version: every prefetch value is an individually
// NAMED float2 (token-pasted, zero dynamic indexing -> cannot be demoted),
// 3 named sets (A,B,C) in cyclic rotation, 2 chunks in flight (16 loads/wave
// sustained = 64 KB/CU vs R9's 32 KB burst-drain). Producers barrier with
// lgkmcnt(0) only (vmcnt never drained; compiler's counted vmcnt at each
// set's first use is the only load wait, ~2 chunk-intervals of slack).
// R10 ran+passed => raw s_barrier structure is container-safe.

__global__ __launch_bounds__(576, 1) void bg_kernel(
    const float* __restrict__ x,      // [T,B,2]
    const float* __restrict__ dopa,   // [T,B]
    const float* __restrict__ Wd1,    // [128,2]
    const float* __restrict__ Wd2,    // [128,2]
    const float* __restrict__ nd1,    // [T,B,128]
    const float* __restrict__ nd2,    // [T,B,128]
    float* __restrict__ out)          // [T,B]
{
#pragma clang fp contract(off)
    constexpr int T = 512, B = 256;
    constexpr int S = 32;             // steps per chunk
    constexpr int NCH = T / S;        // 16 chunks
    constexpr size_t TSTRIDE = (size_t)B * 128;   // noise t-stride (floats)

    __shared__ float lds_I[2][S][64][4];   // 64 KB: double-buffered currents
    __shared__ float lds_x[T][2];          // 4 KB
    __shared__ float lds_d[T];             // 2 KB

    const int b    = blockIdx.x;
    const int tid  = threadIdx.x;
    const int wv   = tid >> 6;        // 0 = consumer, 1..8 = producers
    const int lane = tid & 63;

    // ---- prologue A: stage x/dopa (all 576 threads) ----
    for (int t = tid; t < T; t += 576) {
        const float2 xv = *(const float2*)(x + (size_t)t * (B * 2) + b * 2);
        lds_x[t][0] = xv.x;
        lds_x[t][1] = xv.y;
        lds_d[t]    = dopa[(size_t)t * B + b];
    }
    __syncthreads();

    if (wv == 0) {
        // ================= CONSUMER (R5/R9's verified form) ======
        __syncthreads();   // matches producers' prologue barrier

        float v1a = 0.0f, v1b = 0.0f;
        float v2a = 0.0f, v2b = 0.0f;
        float v_stn = 0.0f, v_gpi = 0.0f;
        float gate_reg = 0.0f;

        for (int i = 0; i < NCH; ++i) {
            const float (*buf)[64][4] = lds_I[i & 1];

#pragma unroll
            for (int s = 0; s < S; ++s) {
                const float4 I = *(const float4*)&buf[s][lane][0];

                // ---- bit-identical recurrence (R2..R9 verified) ----
                v1a = 0.8f * v1a + 0.2f * I.x;
                v1b = 0.8f * v1b + 0.2f * I.y;
                v2a = 0.8f * v2a + 0.2f * I.z;
                v2b = 0.8f * v2b + 0.2f * I.w;

                const bool s1a = v1a >= 0.5f, s1b = v1b >= 0.5f;
                const bool s2a = v2a >= 0.5f, s2b = v2b >= 0.5f;
                v1a = s1a ? 0.0f : v1a;
                v1b = s1b ? 0.0f : v1b;
                v2a = s2a ? 0.0f : v2a;
                v2b = s2b ? 0.0f : v2b;

                const int c1 = __popcll(__ballot(s1a)) + __popcll(__ballot(s1b));
                const int c2 = __popcll(__ballot(s2a)) + __popcll(__ballot(s2b));
                const float mean1 = (float)c1 * 0.0078125f;
                const float mean2 = (float)c2 * 0.0078125f;

                const float I_stn = mean2 * 0.5f;
                v_stn = 0.8f * v_stn + 0.2f * I_stn;
                const float s_stn = (v_stn >= 0.5f) ? 1.0f : 0.0f;
                v_stn = (v_stn >= 0.5f) ? 0.0f : v_stn;

                const float I_gpi = (0.4f + mean1 * -0.8f) + s_stn * 0.6f;
                v_gpi = 0.8f * v_gpi + 0.2f * I_gpi;
                const float s_gpi = (v_gpi >= 0.5f) ? 1.0f : 0.0f;
                v_gpi = (v_gpi >= 0.5f) ? 0.0f : v_gpi;

                const float gate = mean1 - s_gpi;   // wave-uniform

                // lane ((i&1)*32 + s) latches step i*32+s's gate
                const int latch = ((i & 1) << 5) | s;
                gate_reg = (lane == latch) ? gate : gate_reg;
            }

            if (i & 1) {
                const int t0 = (i - 1) * S;
                out[(size_t)(t0 + lane) * B + b] = gate_reg;
            }

            __syncthreads();
        }
    } else {
        // ================= PRODUCERS (waves 1..8) =================
        const float4 w1 = *(const float4*)(Wd1 + 4 * lane);
        const float4 w2 = *(const float4*)(Wd2 + 4 * lane);
        const float* n1b = nd1 + (size_t)b * 128 + 2 * lane;
        const float* n2b = nd2 + (size_t)b * 128 + 2 * lane;
        const int p0 = (wv - 1) * 4;   // this wave covers steps p0..p0+3

        // 3 NAMED register sets, cyclic: chunk c lives in set {A,B,C}[c%3].
        // No arrays, no dynamic indexing => cannot be demoted to scratch.
        float2 r1_A_0, r1_A_1, r1_A_2, r1_A_3, r2_A_0, r2_A_1, r2_A_2, r2_A_3;
        float2 r1_B_0, r1_B_1, r1_B_2, r1_B_3, r2_B_0, r2_B_1, r2_B_2, r2_B_3;
        float2 r1_C_0, r1_C_1, r1_C_2, r1_C_3, r2_C_0, r2_C_1, r2_C_2, r2_C_3;

        // Issue the 8 loads (float2 x 4 steps x 2 arrays) for chunk c.
#define LOADC(c, SET)                                                        \
        if ((c) < NCH) {                                                     \
            const float* bp1 = n1b + (size_t)((c) * S + p0) * TSTRIDE;       \
            const float* bp2 = n2b + (size_t)((c) * S + p0) * TSTRIDE;       \
            r1_##SET##_0 = *(const float2*)(bp1 + 0 * TSTRIDE);              \
            r2_##SET##_0 = *(const float2*)(bp2 + 0 * TSTRIDE);              \
            r1_##SET##_1 = *(const float2*)(bp1 + 1 * TSTRIDE);              \
            r2_##SET##_1 = *(const float2*)(bp2 + 1 * TSTRIDE);              \
            r1_##SET##_2 = *(const float2*)(bp1 + 2 * TSTRIDE);              \
            r2_##SET##_2 = *(const float2*)(bp2 + 2 * TSTRIDE);              \
            r1_##SET##_3 = *(const float2*)(bp1 + 3 * TSTRIDE);              \
            r2_##SET##_3 = *(const float2*)(bp2 + 3 * TSTRIDE);              \
        }

        // One step's I from named regs. EXACT R2..R9 op sequence — bit-exact.
#define COMPJ(c, SET, j, bf) {                                               \
            const int s = p0 + (j);                                          \
            const int t = (c) * S + s;                                       \
            const float xx = lds_x[t][0], xy = lds_x[t][1];                  \
            const float dop = lds_d[t];                                      \
            const float m1 = 1.0f + dop * 0.5f;                              \
            const float m2 = 1.0f - dop * 0.3f;                              \
            const float dot1a = __builtin_fmaf(xy, w1.y, xx * w1.x);         \
            const float dot1b = __builtin_fmaf(xy, w1.w, xx * w1.z);         \
            const float dot2a = __builtin_fmaf(xy, w2.y, xx * w2.x);         \
            const float dot2b = __builtin_fmaf(xy, w2.w, xx * w2.z);         \
            float4 I;                                                        \
            I.x = dot1a * m1 + r1_##SET##_##j.x * 0.1f;                      \
            I.y = dot1b * m1 + r1_##SET##_##j.y * 0.1f;                      \
            I.z = dot2a * m2 + r2_##SET##_##j.x * 0.1f;                      \
            I.w = dot2b * m2 + r2_##SET##_##j.y * 0.1f;                      \
            *(float4*)&lds_I[bf][s][lane][0] = I;                            \
        }

#define COMPC(c, SET, bf)                                                    \
        if ((c) < NCH) {                                                     \
            COMPJ(c, SET, 0, bf)                                             \
            COMPJ(c, SET, 1, bf)                                             \
            COMPJ(c, SET, 2, bf)                                             \
            COMPJ(c, SET, 3, bf)                                             \
        }

        // Raw barrier: ds_writes must be visible (lgkmcnt 0) but global
        // loads stay in flight across it (vmcnt untouched).
#define PBAR                                                                 \
        __builtin_amdgcn_sched_barrier(0);                                   \
        asm volatile("s_waitcnt lgkmcnt(0)" ::: "memory");                   \
        __builtin_amdgcn_sched_barrier(0);                                   \
        __builtin_amdgcn_s_barrier();                                        \
        __builtin_amdgcn_sched_barrier(0);

        // iter i: issue loads for chunk i+3 into set[(i+3)%3] = set[i%3];
        // compute chunk i+1 from set[(i+1)%3]; barrier. Straight-line code.
#define ITER(i, SL, SC)                                                      \
        LOADC((i) + 3, SL)                                                   \
        COMPC((i) + 1, SC, ((i) + 1) & 1)                                    \
        PBAR

        // prologue B: chunks 0(A),1(B),2(C) issued; chunk 0 computed
        LOADC(0, A)
        LOADC(1, B)
        LOADC(2, C)
        COMPC(0, A, 0)
        PBAR

        ITER(0,  A, B)  ITER(1,  B, C)  ITER(2,  C, A)
        ITER(3,  A, B)  ITER(4,  B, C)  ITER(5,  C, A)
        ITER(6,  A, B)  ITER(7,  B, C)  ITER(8,  C, A)
        ITER(9,  A, B)  ITER(10, B, C)  ITER(11, C, A)
        ITER(12, A, B)  ITER(13, B, C)  ITER(14, C, A)
        ITER(15, A, B)
#undef LOADC
#undef COMPJ
#undef COMPC
#undef PBAR
#undef ITER
    }
}

extern "C" void kernel_launch(void* const* d_in, const int* in_sizes, int n_in,
                              void* d_out, int out_size, void* d_ws, size_t ws_size,
                              hipStream_t stream) {
    const float* x    = (const float*)d_in[0];
    const float* dopa = (const float*)d_in[1];
    // d_in[2] = rpe — unused by the reference
    const float* Wd1  = (const float*)d_in[3];
    const float* Wd2  = (const float*)d_in[4];
    const float* nd1  = (const float*)d_in[5];
    const float* nd2  = (const float*)d_in[6];
    float* out = (float*)d_out;

    bg_kernel<<<dim3(256), dim3(576), 0, stream>>>(x, dopa, Wd1, Wd2, nd1, nd2, out);
}

// Round 7
// 188.992 us; speedup vs baseline: 1.2646x; 1.0369x over previous
//
#include <hip/hip_runtime.h>

// Spiking basal ganglia: T=512 serial LIF steps, B=256 circuits.
// R12: attack the CONSUMER. R11 proved the producer pipeline real (no spill,
// loads in flight across barriers) yet 83us == R9's 81us; R9 proved L3-warm
// (49 GB/s) == cold (936 GB/s). All producer theories dead. Accounting says
// the consumer wave's 389 cyc/step = ~95 cyc issue (45 VALU with contract-
// off mul/mul/add) + exposed ds_read latency + ballot SALU crossings.
// Changes: (1) wave 9 = post-processor runs the wave-uniform stn/gpi/gate
// tail + output store one chunk-pair behind (verbatim op sequence ->
// bit-exact), consumer only latches packed (c1,c2) counts; (2) consumer
// reads LDS currents in 8-deep named float4 batches (one latency exposure
// per 8 steps). Producers: R9's proven burst form, untouched. 640 threads.

__global__ __launch_bounds__(640, 1) void bg_kernel(
    const float* __restrict__ x,      // [T,B,2]
    const float* __restrict__ dopa,   // [T,B]
    const float* __restrict__ Wd1,    // [128,2]
    const float* __restrict__ Wd2,    // [128,2]
    const float* __restrict__ nd1,    // [T,B,128]
    const float* __restrict__ nd2,    // [T,B,128]
    float* __restrict__ out)          // [T,B]
{
#pragma clang fp contract(off)
    constexpr int T = 512, B = 256;
    constexpr int S = 32;             // steps per chunk
    constexpr int NCH = T / S;        // 16 chunks
    constexpr size_t TSTRIDE = (size_t)B * 128;   // noise t-stride (floats)

    __shared__ float lds_I[3][S][64][4];   // 96 KB: triple-buffered currents
    __shared__ float lds_x[T][2];          // 4 KB
    __shared__ float lds_d[T];             // 2 KB
    __shared__ unsigned int cnt_lds[2][64];// 512 B: packed (c1,c2) per step,
                                           // double-buffered by chunk-pair

    const int b    = blockIdx.x;
    const int tid  = threadIdx.x;
    const int wv   = tid >> 6;        // 0=consumer, 1..8=producers, 9=post
    const int lane = tid & 63;

    // ---- prologue A: stage x/dopa (all 640 threads) ----
    for (int t = tid; t < T; t += 640) {
        const float2 xv = *(const float2*)(x + (size_t)t * (B * 2) + b * 2);
        lds_x[t][0] = xv.x;
        lds_x[t][1] = xv.y;
        lds_d[t]    = dopa[(size_t)t * B + b];
    }
    __syncthreads();

    if (wv == 0) {
        // ================= CONSUMER: membranes + ballots only =============
        __syncthreads();   // matches producers' prologue-B barrier

        float v1a = 0.0f, v1b = 0.0f;
        float v2a = 0.0f, v2b = 0.0f;
        unsigned int cnt_reg = 0u;

        for (int i = 0; i < NCH; ++i) {
            const float (*buf)[64][4] = lds_I[i % 3];

#pragma unroll
            for (int g = 0; g < 4; ++g) {
                // 8-deep read batch: one LDS latency exposure per 8 steps.
                float4 P[8];
#pragma unroll
                for (int k = 0; k < 8; ++k)
                    P[k] = *(const float4*)&buf[g * 8 + k][lane][0];

#pragma unroll
                for (int k = 0; k < 8; ++k) {
                    const int s = g * 8 + k;
                    const float4 I = P[k];

                    // ---- bit-identical membrane recurrence (R2..R11) ----
                    v1a = 0.8f * v1a + 0.2f * I.x;
                    v1b = 0.8f * v1b + 0.2f * I.y;
                    v2a = 0.8f * v2a + 0.2f * I.z;
                    v2b = 0.8f * v2b + 0.2f * I.w;

                    const bool s1a = v1a >= 0.5f, s1b = v1b >= 0.5f;
                    const bool s2a = v2a >= 0.5f, s2b = v2b >= 0.5f;
                    v1a = s1a ? 0.0f : v1a;
                    v1b = s1b ? 0.0f : v1b;
                    v2a = s2a ? 0.0f : v2a;
                    v2b = s2b ? 0.0f : v2b;

                    const int c1 = __popcll(__ballot(s1a)) + __popcll(__ballot(s1b));
                    const int c2 = __popcll(__ballot(s2a)) + __popcll(__ballot(s2b));

                    // pack counts (SALU); lane ((i&1)*32+s) latches step i*32+s
                    const unsigned int packed =
                        (unsigned int)c1 | ((unsigned int)c2 << 8);
                    const int latch = ((i & 1) << 5) | s;
                    cnt_reg = (lane == latch) ? packed : cnt_reg;
                }
            }

            if (i & 1) {
                // publish counts for steps (i-1)*32 .. i*32+31 (pair (i-1)/2)
                cnt_lds[(i >> 1) & 1][lane] = cnt_reg;
            }

            __syncthreads();
        }
    } else if (wv <= 8) {
        // ================= PRODUCERS (waves 1..8) — R9 verbatim ===========
        const float4 w1 = *(const float4*)(Wd1 + 4 * lane);
        const float4 w2 = *(const float4*)(Wd2 + 4 * lane);
        const float* n1b = nd1 + (size_t)b * 128 + 2 * lane;
        const float* n2b = nd2 + (size_t)b * 128 + 2 * lane;
        const int p0 = (wv - 1) * 4;   // this wave covers steps p0..p0+3

        auto stage = [&](int c, int bf) {
            const int tbase = c * S;
            float2 a1[4], a2[4];
#pragma unroll
            for (int j = 0; j < 4; ++j) {
                const int t = tbase + p0 + j;
                a1[j] = *(const float2*)(n1b + (size_t)t * TSTRIDE);
                a2[j] = *(const float2*)(n2b + (size_t)t * TSTRIDE);
            }
#pragma unroll
            for (int j = 0; j < 4; ++j) {
                const int s = p0 + j;
                const int t = tbase + s;
                const float xx = lds_x[t][0], xy = lds_x[t][1];
                const float dop = lds_d[t];

                const float m1 = 1.0f + dop * 0.5f;
                const float m2 = 1.0f - dop * 0.3f;

                const float dot1a = __builtin_fmaf(xy, w1.y, xx * w1.x);
                const float dot1b = __builtin_fmaf(xy, w1.w, xx * w1.z);
                const float dot2a = __builtin_fmaf(xy, w2.y, xx * w2.x);
                const float dot2b = __builtin_fmaf(xy, w2.w, xx * w2.z);

                float4 I;
                I.x = dot1a * m1 + a1[j].x * 0.1f;
                I.y = dot1b * m1 + a1[j].y * 0.1f;
                I.z = dot2a * m2 + a2[j].x * 0.1f;
                I.w = dot2b * m2 + a2[j].y * 0.1f;

                *(float4*)&lds_I[bf][s][lane][0] = I;
            }
        };

        // prologue B: chunks 0 and 1
        stage(0, 0);
        stage(1, 1);
        __syncthreads();

        for (int i = 0; i < NCH; ++i) {
            if (i + 2 < NCH) stage(i + 2, (i + 2) % 3);
            __syncthreads();
        }
    } else {
        // ================= POST-PROCESSOR (wave 9) ========================
        // Runs the wave-uniform stn/gpi/gate chain one chunk-pair behind,
        // fully overlapped with the consumer's next chunks. Bit-exact:
        // verbatim op sequence from the R2..R11 consumer.
        __syncthreads();   // matches producers' prologue-B barrier

        float v_stn = 0.0f, v_gpi = 0.0f;

        auto process_pair = [&](int p) {
            const unsigned int cnts = cnt_lds[p & 1][lane];
            // lane j holds step p*64+j's counts; precompute means vectorized
            const float mean1v = (float)(int)(cnts & 0xffu) * 0.0078125f;
            const float mean2v = (float)(int)(cnts >> 8) * 0.0078125f;

            float gate_reg = 0.0f;
#pragma unroll
            for (int j = 0; j < 64; ++j) {
                const float mean1 = __shfl(mean1v, j);
                const float mean2 = __shfl(mean2v, j);

                const float I_stn = mean2 * 0.5f;
                v_stn = 0.8f * v_stn + 0.2f * I_stn;
                const float s_stn = (v_stn >= 0.5f) ? 1.0f : 0.0f;
                v_stn = (v_stn >= 0.5f) ? 0.0f : v_stn;

                const float I_gpi = (0.4f + mean1 * -0.8f) + s_stn * 0.6f;
                v_gpi = 0.8f * v_gpi + 0.2f * I_gpi;
                const float s_gpi = (v_gpi >= 0.5f) ? 1.0f : 0.0f;
                v_gpi = (v_gpi >= 0.5f) ? 0.0f : v_gpi;

                const float gate = mean1 - s_gpi;   // wave-uniform

                gate_reg = (lane == j) ? gate : gate_reg;
            }
            // store 64 gates for steps p*64 .. p*64+63 (same mapping as R9)
            out[(size_t)(p * 64 + lane) * B + b] = gate_reg;
        };

        for (int i = 0; i < NCH; ++i) {
            // pair p's counts are published before barrier i=2p+1; process
            // during iteration 2p+2. Pairs 0..6 here, pair 7 after the loop.
            if (i >= 2 && (i & 1) == 0) process_pair((i >> 1) - 1);
            __syncthreads();
        }
        process_pair(7);
    }
}

extern "C" void kernel_launch(void* const* d_in, const int* in_sizes, int n_in,
                              void* d_out, int out_size, void* d_ws, size_t ws_size,
                              hipStream_t stream) {
    const float* x    = (const float*)d_in[0];
    const float* dopa = (const float*)d_in[1];
    // d_in[2] = rpe — unused by the reference
    const float* Wd1  = (const float*)d_in[3];
    const float* Wd2  = (const float*)d_in[4];
    const float* nd1  = (const float*)d_in[5];
    const float* nd2  = (const float*)d_in[6];
    float* out = (float*)d_out;

    bg_kernel<<<dim3(256), dim3(640), 0, stream>>>(x, dopa, Wd1, Wd2, nd1, nd2, out);
}